// Round 2
// 175.584 us; speedup vs baseline: 1.0015x; 1.0015x over previous
//
#include <hip/hip_runtime.h>

#define N_NODES 100000
#define DEG 16
#define D_DIM 128
#define U_DIM 128
#define FSTRIDE 136   // bf16 LDS row stride: 272 B -> 68 dwords -> conflicts <= 2-way

typedef __bf16 bf16x8 __attribute__((ext_vector_type(8)));
typedef float f32x4 __attribute__((ext_vector_type(4)));

__device__ __forceinline__ unsigned short f2bf(float x) {
    // round-to-nearest-even fp32 -> bf16 (inputs finite)
    unsigned int u = __float_as_uint(x);
    u += 0x7fffu + ((u >> 16) & 1u);
    return (unsigned short)(u >> 16);
}
__device__ __forceinline__ unsigned int pack2(float a, float b) {
    return (unsigned int)f2bf(a) | ((unsigned int)f2bf(b) << 16);
}

// W fp32 [K=128][U=128] row-major -> WT bf16 [U][K] (A-fragment friendly: k contiguous)
__global__ void cast_w_kernel(const float* __restrict__ W,
                              unsigned short* __restrict__ WT) {
    int t = blockIdx.x * 256 + threadIdx.x;   // t < 16384
    int k = t >> 7, n = t & 127;
    WT[n * 128 + k] = f2bf(W[t]);
}

// Y[n][u] = feat[n,:] @ W[:,u] + b[u], stored bf16 row-major [N][128].
// feat tile (128 nodes) staged ONCE per block into LDS as bf16. A = W^T
// loop-invariant fragments; B from LDS ds_read_b128. D[m=u][n=node] -> uint2 stores.
__global__ __launch_bounds__(256)
void ymat_kernel(const float* __restrict__ feat,
                 const unsigned short* __restrict__ WT,   // bf16 [U][K]
                 const float* __restrict__ bias,
                 unsigned short* __restrict__ Y) {
    __shared__ __align__(16) unsigned short ftile[128 * FSTRIDE];
    const int lane = threadIdx.x & 63;
    const int wv = threadIdx.x >> 6;
    const int quad = lane >> 4;
    const int l15 = lane & 15;
    const int n0 = blockIdx.x * 128;
    const int u_base = wv * 32;

    // ---- stage: 16384 floats, thread t handles float4 indices j*256+t (1 KB/instr/wave)
    {
        const int t = threadIdx.x;
        #pragma unroll
        for (int j = 0; j < 16; ++j) {
            const int i = j * 256 + t;          // float4 index in tile
            const int row = i >> 5;
            const int col = (i & 31) * 4;
            const int rowc = (n0 + row < N_NODES) ? (n0 + row) : (N_NODES - 1);
            const float4 v = *(const float4*)(feat + (size_t)rowc * D_DIM + col);
            ushort4 s;
            s.x = f2bf(v.x); s.y = f2bf(v.y); s.z = f2bf(v.z); s.w = f2bf(v.w);
            *(ushort4*)&ftile[row * FSTRIDE + col] = s;
        }
    }

    // A fragments: A[m=l15 -> u][k = kc*32+quad*8+j]
    bf16x8 afr[2][4];
    #pragma unroll
    for (int ni = 0; ni < 2; ++ni) {
        const int u = u_base + ni * 16 + l15;
        #pragma unroll
        for (int kc = 0; kc < 4; ++kc)
            afr[ni][kc] = *(const bf16x8*)(WT + u * 128 + kc * 32 + quad * 8);
    }
    // bias for D rows: u = u_base + ni*16 + quad*4 + r
    const float4 bv0 = *(const float4*)(bias + u_base + quad * 4);
    const float4 bv1 = *(const float4*)(bias + u_base + 16 + quad * 4);

    __syncthreads();

    #pragma unroll
    for (int mi = 0; mi < 8; ++mi) {
        const int node = n0 + mi * 16 + l15;
        bf16x8 bfr[4];
        #pragma unroll
        for (int kc = 0; kc < 4; ++kc)   // B[k][n]: n=l15 -> node row in LDS
            bfr[kc] = *(const bf16x8*)&ftile[(mi * 16 + l15) * FSTRIDE + kc * 32 + quad * 8];
        f32x4 acc0 = (f32x4){0.f, 0.f, 0.f, 0.f};
        f32x4 acc1 = (f32x4){0.f, 0.f, 0.f, 0.f};
        #pragma unroll
        for (int kc = 0; kc < 4; ++kc) {
            acc0 = __builtin_amdgcn_mfma_f32_16x16x32_bf16(afr[0][kc], bfr[kc], acc0, 0, 0, 0);
            acc1 = __builtin_amdgcn_mfma_f32_16x16x32_bf16(afr[1][kc], bfr[kc], acc1, 0, 0, 0);
        }
        if (node < N_NODES) {
            unsigned int* yp = (unsigned int*)(Y + (size_t)node * U_DIM + u_base + quad * 4);
            uint2 s0, s1;
            s0.x = pack2(acc0[0] + bv0.x, acc0[1] + bv0.y);
            s0.y = pack2(acc0[2] + bv0.z, acc0[3] + bv0.w);
            s1.x = pack2(acc1[0] + bv1.x, acc1[1] + bv1.y);
            s1.y = pack2(acc1[2] + bv1.z, acc1[3] + bv1.w);
            *(uint2*)yp = s0;
            *(uint2*)(yp + 8) = s1;   // +16 ushorts
        }
    }
}

// out[n, phase*64 : +64] = relu( (sum_e w_e * Y[col_e, half]) / (sum_e w_e) )
// Two u-phases via grid ordering (12.8 MB pool/phase). 16 lanes/node, uint2
// gathers: a 16-lane node-group covers one full 128 B line per edge (aligned,
// fully-used). ALL 16 edge gathers are issued before any consumption
// (sched_barrier fence) -> 16 outstanding lines/thread. Previous 8-lane/uint4
// version was re-rolled by the compiler to VGPR=36 (~4 outstanding): latency-bound.
// Edge loads PLAIN cached (R7: nt loads refetch +9 MB in phase 1: +2.4 us).
__global__ __launch_bounds__(256, 4)
void agg_kernel(const unsigned short* __restrict__ Y,
                const int* __restrict__ cols,
                const float* __restrict__ wts,
                float* __restrict__ out) {
    const int phase = (blockIdx.x >= 6250) ? 1 : 0;
    const int nb = blockIdx.x - phase * 6250;
    const int node = nb * 16 + (threadIdx.x >> 4);   // exact: 6250*16 = N_NODES
    const int ubase = phase * 64 + (threadIdx.x & 15) * 4;   // owns 4 dims
    const int e0 = node * DEG;

    int cc[DEG];
    float ww[DEG];
    #pragma unroll
    for (int q = 0; q < 4; ++q) {
        const int4 c4 = *(const int4*)(cols + e0 + 4 * q);
        const float4 w4 = *(const float4*)(wts + e0 + 4 * q);
        cc[4 * q + 0] = c4.x; cc[4 * q + 1] = c4.y;
        cc[4 * q + 2] = c4.z; cc[4 * q + 3] = c4.w;
        ww[4 * q + 0] = w4.x; ww[4 * q + 1] = w4.y;
        ww[4 * q + 2] = w4.z; ww[4 * q + 3] = w4.w;
    }

    // issue ALL 16 gathers before any use: 16 outstanding 128B lines per thread
    uint2 p[DEG];
    #pragma unroll
    for (int e = 0; e < DEG; ++e)
        p[e] = *(const uint2*)(Y + (size_t)cc[e] * U_DIM + ubase);
    __builtin_amdgcn_sched_barrier(0);   // keep the load cluster intact

    float den = 0.f;
    #pragma unroll
    for (int e = 0; e < DEG; ++e) den += ww[e];

    float a0 = 0.f, a1 = 0.f, a2 = 0.f, a3 = 0.f;
    #pragma unroll
    for (int e = 0; e < DEG; ++e) {
        const float w = ww[e];
        a0 = fmaf(w, __uint_as_float(p[e].x << 16), a0);
        a1 = fmaf(w, __uint_as_float(p[e].x & 0xffff0000u), a1);
        a2 = fmaf(w, __uint_as_float(p[e].y << 16), a2);
        a3 = fmaf(w, __uint_as_float(p[e].y & 0xffff0000u), a3);
    }
    const float inv = 1.0f / den;           // den >= 0.1*16
    f32x4 o;
    o[0] = fmaxf(a0 * inv, 0.f); o[1] = fmaxf(a1 * inv, 0.f);
    o[2] = fmaxf(a2 * inv, 0.f); o[3] = fmaxf(a3 * inv, 0.f);
    __builtin_nontemporal_store(o, (f32x4*)(out + (size_t)node * U_DIM + ubase));
}

extern "C" void kernel_launch(void* const* d_in, const int* in_sizes, int n_in,
                              void* d_out, int out_size, void* d_ws, size_t ws_size,
                              hipStream_t stream) {
    const float* feat = (const float*)d_in[0];
    // d_in[1] = edge_rows: unused — rows are arange(E)//DEG, node i owns edges [16i,16i+16)
    const int* cols  = (const int*)d_in[2];
    const float* wts = (const float*)d_in[3];
    const float* W   = (const float*)d_in[4];
    const float* b   = (const float*)d_in[5];
    float* out = (float*)d_out;

    unsigned short* wt_bf = (unsigned short*)d_ws;                    // 32 KB bf16 [U][K]
    unsigned short* Y     = (unsigned short*)((char*)d_ws + 32768);   // 25.6 MB bf16 [N][128]

    cast_w_kernel<<<16384 / 256, 256, 0, stream>>>(W, wt_bf);

    const int nblocks = (N_NODES + 127) / 128;   // 782
    ymat_kernel<<<nblocks, 256, 0, stream>>>(feat, wt_bf, b, Y);

    agg_kernel<<<12500, 256, 0, stream>>>(Y, cols, wts, out);
}